// Round 13
// baseline (38.701 us; speedup 1.0000x reference)
//
#include <hip/hip_runtime.h>
#include <hip/hip_bf16.h>

// Problem constants (from reference): B=8192, MN=64*64=4096, D=128
#define NB   8192
#define NMN  4096
#define ND   128

typedef __attribute__((ext_vector_type(8))) short bf16x8;  // 8 bf16 = 16 B
typedef __attribute__((ext_vector_type(8))) short short8;
typedef __attribute__((ext_vector_type(4))) float f32x4;

// ---------------------------------------------------------------------------
// Packed fragment layout for MFMA operands:
//   array viewed in 16B chunks: chunk_idx = (row>>4)*256 + q*16 + (row&15)
// where q = 16B k-chunk (8 bf16 along K), row = matrix row.
// A wave's fragment load (fixed panel, fixed kk) reads chunks
//   base + l4*16 + l15  -> 64 consecutive 16B chunks = 1 KB contiguous.
// ---------------------------------------------------------------------------

// Prep: fp32 -> bf16 packed layout + exact fp32 row-norms. (unchanged)
__global__ __launch_bounds__(256) void som_prep(const float* __restrict__ batch,
                                                const float* __restrict__ weights,
                                                __hip_bfloat16* __restrict__ apk,
                                                __hip_bfloat16* __restrict__ wpk,
                                                float* __restrict__ a2,
                                                float* __restrict__ b2) {
    const int wid  = threadIdx.x >> 6;
    const int lane = threadIdx.x & 63;
    const int rof  = lane >> 4;    // row within wave's 4-row group
    const int q    = lane & 15;    // 16B k-chunk index (8 floats)

    int row = blockIdx.x * 16 + wid * 4 + rof;   // 768 blocks * 16 rows

    const float* src;
    __hip_bfloat16* dst;
    float* norm;
    if (row < NB) {
        src = batch;  dst = apk; norm = a2;
    } else {
        row -= NB;
        src = weights; dst = wpk; norm = b2;
    }

    const f32x4 v0 = *reinterpret_cast<const f32x4*>(src + (size_t)row * ND + q * 8);
    const f32x4 v1 = *reinterpret_cast<const f32x4*>(src + (size_t)row * ND + q * 8 + 4);

    __hip_bfloat16 tmp[8];
    tmp[0] = __float2bfloat16(v0.x); tmp[1] = __float2bfloat16(v0.y);
    tmp[2] = __float2bfloat16(v0.z); tmp[3] = __float2bfloat16(v0.w);
    tmp[4] = __float2bfloat16(v1.x); tmp[5] = __float2bfloat16(v1.y);
    tmp[6] = __float2bfloat16(v1.z); tmp[7] = __float2bfloat16(v1.w);

    const int chunk = (row >> 4) * 256 + q * 16 + (row & 15);
    *reinterpret_cast<short8*>(dst + (size_t)chunk * 8) =
        *reinterpret_cast<short8*>(tmp);

    float p = v0.x * v0.x + v0.y * v0.y + v0.z * v0.z + v0.w * v0.w
            + v1.x * v1.x + v1.y * v1.y + v1.z * v1.z + v1.w * v1.w;
    #pragma unroll
    for (int off = 1; off < 16; off <<= 1) p += __shfl_xor(p, off, 64);
    if (q == 0) norm[row] = p;
}

// ---------------------------------------------------------------------------
// PERSISTENT GEMM, SLIM TILES for 4 blocks/CU (occupancy experiment).
// 128x64 tile, 4 waves in 2x2 (each wave 64 batch x 32 weight):
//   acc[4][2]=32 + wgt[4][2]=32 + bat[4]=16 VGPR  ->  ~110 total, fits the
//   128-VGPR budget of __launch_bounds__(256,4) WITHOUT spills (round 7's
//   confound). 4 blocks/CU = 4 independent store streams per CU.
// 1024 blocks x 4 tiles. Swizzle w0=(bx&7)*512+(bx>>3), tile i at w0+128*i:
//   XCD (bx&7) and col-block (w0&63) invariant -> fixed W panel per block
//   (W fragments + b2 loaded once), contiguous per-XCD output band per step.
// Epilogue: per-wave LDS transpose (16x32 f32 strip) -> 128B-contiguous NT
// stores (store micro-pattern proven immaterial rounds 4/5/9/10).
// ---------------------------------------------------------------------------
__global__ __launch_bounds__(256, 4) void som_gemm(const __hip_bfloat16* __restrict__ apk_,
                                                   const __hip_bfloat16* __restrict__ wpk_,
                                                   const float* __restrict__ a2,
                                                   const float* __restrict__ b2,
                                                   float* __restrict__ out) {
    const int bx = blockIdx.x;          // 0..1023
    const int w0 = (bx & 7) * 512 + (bx >> 3);
    const int bcol = (w0 & 63) << 6;    // 64-wide col block, constant
    const int rb0  = w0 >> 6;           // row-block base

    const int tid  = threadIdx.x;
    const int lane = tid & 63;
    const int wid  = tid >> 6;
    const int wr   = wid >> 1;          // wave row (batch dim) 0..1
    const int wc   = wid & 1;           // wave col (weight dim) 0..1
    const int l15  = lane & 15;
    const int l4   = lane >> 4;

    const bf16x8* A = reinterpret_cast<const bf16x8*>(apk_);
    const bf16x8* W = reinterpret_cast<const bf16x8*>(wpk_);

    __shared__ float strip[4][16][32];   // 8 KB, one 2KB strip per wave
    f32x4* strip16 = reinterpret_cast<f32x4*>(&strip[wid][0][0]);

    // ---- load ALL weight fragments once (fixed 32-col wave panel) ----
    const int woff = ((bcol >> 4) + wc * 2) * 256 + l4 * 16 + l15;
    bf16x8 wgt[4][2];                    // [kk][n]
    #pragma unroll
    for (int kk = 0; kk < 4; ++kk)
        #pragma unroll
        for (int n = 0; n < 2; ++n)
            wgt[kk][n] = W[woff + n * 256 + kk * 64];

    f32x4 b2v[2];
    #pragma unroll
    for (int n = 0; n < 2; ++n)
        b2v[n] = *reinterpret_cast<const f32x4*>(&b2[bcol + wc * 32 + n * 16 + l4 * 4]);

    const int ocol = bcol + wc * 32 + (lane & 7) * 4;   // drain column base
    const int rdr  = lane >> 3;                          // drain row 0..7

    // ---- 4 tiles: row-block rb0 + 2*i ----
    #pragma unroll
    for (int i = 0; i < 4; ++i) {
        const int brow = (rb0 + 2 * i) << 7;
        const int aoff = ((brow >> 4) + wr * 4) * 256 + l4 * 16 + l15;

        f32x4 acc[4][2];   // [m = batch frag][n = weight frag]
        #pragma unroll
        for (int m = 0; m < 4; ++m)
            #pragma unroll
            for (int n = 0; n < 2; ++n)
                acc[m][n] = (f32x4){0.f, 0.f, 0.f, 0.f};

        #pragma unroll
        for (int kk = 0; kk < 4; ++kk) {
            bf16x8 bat[4];
            #pragma unroll
            for (int m = 0; m < 4; ++m) bat[m] = A[aoff + m * 256 + kk * 64];
            #pragma unroll
            for (int m = 0; m < 4; ++m)
                #pragma unroll
                for (int n = 0; n < 2; ++n)
                    acc[m][n] = __builtin_amdgcn_mfma_f32_16x16x32_bf16(wgt[kk][n], bat[m], acc[m][n], 0, 0, 0);
        }

        float a2v[4];
        #pragma unroll
        for (int m = 0; m < 4; ++m) a2v[m] = a2[brow + wr * 64 + m * 16 + l15];

        const size_t orow_base = (size_t)(brow + wr * 64);

        #pragma unroll
        for (int m = 0; m < 4; ++m) {
            // stage: strip[row=l15][chunk = (n*4+l4) ^ (l15&7)]  (16B chunks, 8/row)
            #pragma unroll
            for (int n = 0; n < 2; ++n) {
                f32x4 val = a2v[m] + b2v[n] - 2.0f * acc[m][n];
                strip16[l15 * 8 + ((n * 4 + l4) ^ (l15 & 7))] = val;
            }
            // drain: row r = rdr + 8j, chunk c = lane&7 stored at c ^ (r&7)
            #pragma unroll
            for (int j = 0; j < 2; ++j) {
                const int r = rdr + 8 * j;
                f32x4 val = strip16[r * 8 + ((lane & 7) ^ (r & 7))];
                __builtin_nontemporal_store(val,
                    reinterpret_cast<f32x4*>(out + (orow_base + m * 16 + r) * NMN + ocol));
            }
        }
    }
}

// ---------------------------------------------------------------------------
extern "C" void kernel_launch(void* const* d_in, const int* in_sizes, int n_in,
                              void* d_out, int out_size, void* d_ws, size_t ws_size,
                              hipStream_t stream) {
    const float* batch   = (const float*)d_in[0];   // (8192, 128) fp32
    const float* weights = (const float*)d_in[1];   // (4096, 128) fp32
    float* out = (float*)d_out;                     // (8192, 4096) fp32

    // workspace layout:
    //   a2  : 8192 * 4          =   32768 B @ 0
    //   b2  : 4096 * 4          =   16384 B @ 32768
    //   apk : 8192 * 128 * 2    = 2097152 B @ 49152   (packed fragment layout)
    //   wpk : 4096 * 128 * 2    = 1048576 B @ 2146304
    char* ws = (char*)d_ws;
    float* a2 = (float*)(ws);
    float* b2 = (float*)(ws + 32768);
    __hip_bfloat16* apk = (__hip_bfloat16*)(ws + 49152);
    __hip_bfloat16* wpk = (__hip_bfloat16*)(ws + 49152 + 2097152);

    som_prep<<<dim3((NB + NMN) / 16), dim3(256), 0, stream>>>(batch, weights, apk, wpk, a2, b2);

    // persistent: 1024 blocks (4/CU), 4 tiles each (4096 128x64 tiles)
    som_gemm<<<dim3(1024), dim3(256), 0, stream>>>(apk, wpk, a2, b2, out);
}

// Round 14
// 34.202 us; speedup vs baseline: 1.1315x; 1.1315x over previous
//
#include <hip/hip_runtime.h>
#include <hip/hip_bf16.h>

// Problem constants (from reference): B=8192, MN=64*64=4096, D=128
#define NB   8192
#define NMN  4096
#define ND   128

typedef __attribute__((ext_vector_type(8))) short bf16x8;  // 8 bf16 = 16 B
typedef __attribute__((ext_vector_type(8))) short short8;
typedef __attribute__((ext_vector_type(4))) float f32x4;

// ---------------------------------------------------------------------------
// FINAL KERNEL (round-8 structure, verified 34.3-34.6 us across two runs).
//
// out[b][w] = ||A_b||^2 + ||W_w||^2 - 2 * dot(A_b, W_w)
// Exact fp32 norms + bf16 MFMA cross term (absmax ~1.0 vs threshold 3.92).
//
// Packed fragment layout for MFMA operands (built by som_prep):
//   array viewed in 16B chunks: chunk_idx = (row>>4)*256 + q*16 + (row&15)
// where q = 16B k-chunk (8 bf16 along K). A wave's fragment load reads
// chunks base + l4*16 + l15 -> 1 KB fully contiguous per instruction.
// ---------------------------------------------------------------------------

// Prep: fp32 -> bf16 packed layout + exact fp32 row-norms.
__global__ __launch_bounds__(256) void som_prep(const float* __restrict__ batch,
                                                const float* __restrict__ weights,
                                                __hip_bfloat16* __restrict__ apk,
                                                __hip_bfloat16* __restrict__ wpk,
                                                float* __restrict__ a2,
                                                float* __restrict__ b2) {
    const int wid  = threadIdx.x >> 6;
    const int lane = threadIdx.x & 63;
    const int rof  = lane >> 4;    // row within wave's 4-row group
    const int q    = lane & 15;    // 16B k-chunk index (8 floats)

    int row = blockIdx.x * 16 + wid * 4 + rof;   // 768 blocks * 16 rows

    const float* src;
    __hip_bfloat16* dst;
    float* norm;
    if (row < NB) {
        src = batch;  dst = apk; norm = a2;
    } else {
        row -= NB;
        src = weights; dst = wpk; norm = b2;
    }

    const f32x4 v0 = *reinterpret_cast<const f32x4*>(src + (size_t)row * ND + q * 8);
    const f32x4 v1 = *reinterpret_cast<const f32x4*>(src + (size_t)row * ND + q * 8 + 4);

    __hip_bfloat16 tmp[8];
    tmp[0] = __float2bfloat16(v0.x); tmp[1] = __float2bfloat16(v0.y);
    tmp[2] = __float2bfloat16(v0.z); tmp[3] = __float2bfloat16(v0.w);
    tmp[4] = __float2bfloat16(v1.x); tmp[5] = __float2bfloat16(v1.y);
    tmp[6] = __float2bfloat16(v1.z); tmp[7] = __float2bfloat16(v1.w);

    const int chunk = (row >> 4) * 256 + q * 16 + (row & 15);
    *reinterpret_cast<short8*>(dst + (size_t)chunk * 8) =
        *reinterpret_cast<short8*>(tmp);

    float p = v0.x * v0.x + v0.y * v0.y + v0.z * v0.z + v0.w * v0.w
            + v1.x * v1.x + v1.y * v1.y + v1.z * v1.z + v1.w * v1.w;
    #pragma unroll
    for (int off = 1; off < 16; off <<= 1) p += __shfl_xor(p, off, 64);
    if (q == 0) norm[row] = p;
}

// ---------------------------------------------------------------------------
// PERSISTENT GEMM: 512 blocks (2/CU), each processes 4 tiles: t = bx + 512*i.
// Tile swizzle w = (t&7)*256 + (t>>3): stepping t by 512 keeps (t&7) and
// (w&31) constant -> same XCD, SAME weight panel for all 4 tiles; only the
// batch row-band advances (brow += 256). So:
//   * all 16 W fragments are loaded ONCE into VGPRs and reused (-40% reads)
//   * tile i+1's A-loads/MFMA overlap tile i's NT store drain
//   * no __syncthreads anywhere (per-wave LDS strips, in-order DS ops)
// Operands swapped (weights = MFMA A-op): D col = batch = lane&15, D row =
// weight col = (lane>>4)*4+reg -> each lane's 4 acc regs are 4 consecutive
// output columns. Epilogue: per-wave LDS transpose -> 256B-contiguous NT
// stores (store micro-pattern proven immaterial rounds 4/5/9/10).
// ---------------------------------------------------------------------------
__global__ __launch_bounds__(256) void som_gemm(const __hip_bfloat16* __restrict__ apk_,
                                                const __hip_bfloat16* __restrict__ wpk_,
                                                const float* __restrict__ a2,
                                                const float* __restrict__ b2,
                                                float* __restrict__ out) {
    const int bx = blockIdx.x;          // 0..511
    const int w0 = (bx & 7) * 256 + (bx >> 3);
    const int bcol = (w0 & 31) << 7;    // constant across this block's tiles

    const int tid  = threadIdx.x;
    const int lane = tid & 63;
    const int wid  = tid >> 6;
    const int wr   = wid >> 1;          // wave row (batch dim) 0..1
    const int wc   = wid & 1;           // wave col (weight dim) 0..1
    const int l15  = lane & 15;
    const int l4   = lane >> 4;

    const bf16x8* A = reinterpret_cast<const bf16x8*>(apk_);
    const bf16x8* W = reinterpret_cast<const bf16x8*>(wpk_);

    __shared__ float strip[4][16][64];   // 16 KB, one 4KB strip per wave
    f32x4* strip16 = reinterpret_cast<f32x4*>(&strip[wid][0][0]);

    // ---- load ALL weight fragments once (fixed panel) ----
    const int woff = ((bcol >> 4) + wc * 4) * 256 + l4 * 16 + l15;
    bf16x8 wgt[4][4];                    // [kk][n]
    #pragma unroll
    for (int kk = 0; kk < 4; ++kk)
        #pragma unroll
        for (int n = 0; n < 4; ++n)
            wgt[kk][n] = W[woff + n * 256 + kk * 64];

    f32x4 b2v[4];
    #pragma unroll
    for (int n = 0; n < 4; ++n)
        b2v[n] = *reinterpret_cast<const f32x4*>(&b2[bcol + wc * 64 + n * 16 + l4 * 4]);

    const int ocol = bcol + wc * 64 + l15 * 4;

    // ---- 4 tiles: brow = ((w0>>5) + 2*i) * 128 ----
    #pragma unroll
    for (int i = 0; i < 4; ++i) {
        const int brow = ((w0 >> 5) + 2 * i) << 7;
        const int aoff = ((brow >> 4) + wr * 4) * 256 + l4 * 16 + l15;

        f32x4 acc[4][4];   // [m = batch frag][n = weight frag]
        #pragma unroll
        for (int m = 0; m < 4; ++m)
            #pragma unroll
            for (int n = 0; n < 4; ++n)
                acc[m][n] = (f32x4){0.f, 0.f, 0.f, 0.f};

        #pragma unroll
        for (int kk = 0; kk < 4; ++kk) {
            bf16x8 bat[4];
            #pragma unroll
            for (int m = 0; m < 4; ++m) bat[m] = A[aoff + m * 256 + kk * 64];
            #pragma unroll
            for (int m = 0; m < 4; ++m)
                #pragma unroll
                for (int n = 0; n < 4; ++n)
                    acc[m][n] = __builtin_amdgcn_mfma_f32_16x16x32_bf16(wgt[kk][n], bat[m], acc[m][n], 0, 0, 0);
        }

        float a2v[4];
        #pragma unroll
        for (int m = 0; m < 4; ++m) a2v[m] = a2[brow + wr * 64 + m * 16 + l15];

        const size_t orow_base = (size_t)(brow + wr * 64);

        #pragma unroll
        for (int m = 0; m < 4; ++m) {
            // stage: strip[row=l15][chunk = (n*4+l4) ^ l15]  (16B chunks)
            #pragma unroll
            for (int n = 0; n < 4; ++n) {
                f32x4 val = a2v[m] + b2v[n] - 2.0f * acc[m][n];
                strip16[l15 * 16 + ((n * 4 + l4) ^ l15)] = val;
            }
            // drain: row r = 4j + l4, chunk l15 stored at l15 ^ r
            #pragma unroll
            for (int j = 0; j < 4; ++j) {
                const int r = 4 * j + l4;
                f32x4 val = strip16[r * 16 + (l15 ^ r)];
                __builtin_nontemporal_store(val,
                    reinterpret_cast<f32x4*>(out + (orow_base + m * 16 + r) * NMN + ocol));
            }
        }
    }
}

// ---------------------------------------------------------------------------
extern "C" void kernel_launch(void* const* d_in, const int* in_sizes, int n_in,
                              void* d_out, int out_size, void* d_ws, size_t ws_size,
                              hipStream_t stream) {
    const float* batch   = (const float*)d_in[0];   // (8192, 128) fp32
    const float* weights = (const float*)d_in[1];   // (4096, 128) fp32
    float* out = (float*)d_out;                     // (8192, 4096) fp32

    // workspace layout:
    //   a2  : 8192 * 4          =   32768 B @ 0
    //   b2  : 4096 * 4          =   16384 B @ 32768
    //   apk : 8192 * 128 * 2    = 2097152 B @ 49152   (packed fragment layout)
    //   wpk : 4096 * 128 * 2    = 1048576 B @ 2146304
    char* ws = (char*)d_ws;
    float* a2 = (float*)(ws);
    float* b2 = (float*)(ws + 32768);
    __hip_bfloat16* apk = (__hip_bfloat16*)(ws + 49152);
    __hip_bfloat16* wpk = (__hip_bfloat16*)(ws + 49152 + 2097152);

    som_prep<<<dim3((NB + NMN) / 16), dim3(256), 0, stream>>>(batch, weights, apk, wpk, a2, b2);

    // persistent: 512 blocks, 4 tiles each (2048 tiles total)
    som_gemm<<<dim3(512), dim3(256), 0, stream>>>(apk, wpk, a2, b2, out);
}